// Round 3
// baseline (837.996 us; speedup 1.0000x reference)
//
#include <hip/hip_runtime.h>

#define BB 256
#define TT 1024
#define KK 64
#define NSEG 32   // segments of 32 steps for parallel backtrace

// ---------------------------------------------------------------------------
// Kernel A: path score (unary + transition) and mask count.
// NOTE: mask is int32 on device (harness converts bool -> int32).
// ---------------------------------------------------------------------------
__global__ __launch_bounds__(256) void score_kernel(
    const float* __restrict__ em, const int* __restrict__ tags,
    const int* __restrict__ mask, const float* __restrict__ trans,
    float* ll_sum, int* maskSum) {
  int b = blockIdx.x;
  int tid = threadIdx.x;
  float acc = 0.f;
  int cnt = 0;
  for (int t = tid; t < TT; t += 256) {
    int idx = b * TT + t;
    if (mask[idx]) {
      int tg = tags[idx];
      acc += em[(size_t)idx * KK + tg];
      cnt += 1;
      if (t >= 1) acc += trans[tags[idx - 1] * KK + tg];
    }
  }
  __shared__ float rf[256];
  __shared__ int ri[256];
  rf[tid] = acc; ri[tid] = cnt;
  __syncthreads();
  for (int off = 128; off > 0; off >>= 1) {
    if (tid < off) { rf[tid] += rf[tid + off]; ri[tid] += ri[tid + off]; }
    __syncthreads();
  }
  if (tid == 0) { atomicAdd(ll_sum, rf[0]); atomicAdd(maskSum, ri[0]); }
}

// ---------------------------------------------------------------------------
// Kernel B: merged forward (log Z, exp-domain) + Viterbi + in-LDS backtrace.
// One block (4 waves) per batch. Lane layout: wave w owns states
// j in [16w,16w+16); lane l = ig*16+jl covers i in [16ig,16ig+16) for j.
// Backpointers for ALL t live in LDS (64 KB; gfx950 allows 160 KB/WG).
// ---------------------------------------------------------------------------
__global__ __launch_bounds__(256) void crf_scan_kernel(
    const float* __restrict__ em, const int* __restrict__ mask,
    const float* __restrict__ trans, const int* __restrict__ tags,
    float* __restrict__ out_dec, float* ll_sum, int* match) {
  int b = blockIdx.x;
  int tid = threadIdx.x;
  int w = tid >> 6;
  int l = tid & 63;
  int ig = l >> 4;
  int jl = l & 15;
  int j = (w << 4) + jl;
  int ibase = ig << 4;

  __shared__ float sbuf[2][KK];            // forward vector (exp domain)
  __shared__ float dbuf[2][KK];            // viterbi delta
  __shared__ unsigned char mapb[2][KK];    // running composed map -> seg base
  __shared__ unsigned char segm[NSEG][KK]; // per-segment composed maps
  __shared__ unsigned char bpl[TT][KK];    // backpointers, 64 KB
  __shared__ unsigned char mrow[TT];       // mask row (0/1)
  __shared__ float wmax[4];
  __shared__ unsigned char bound_s[40];    // state at t=32*s (s<=31), [32]=t1023
  __shared__ int redc[NSEG];

  float E[16], C[16];
#pragma unroll
  for (int r = 0; r < 16; ++r) {
    C[r] = trans[(ibase + r) * KK + j];
    E[r] = __expf(C[r]);
  }

  const float* emb = em + (size_t)b * TT * KK;
  const int* mb = mask + (size_t)b * TT;   // int32 mask

  for (int t = tid; t < TT; t += 256) mrow[t] = (unsigned char)(mb[t] ? 1 : 0);
  if (tid < KK) {
    float e0 = emb[tid];
    sbuf[0][tid] = e0;                     // raw, for max
    dbuf[1][tid] = e0;                     // delta0 = emissions[:,0]
    mapb[1][tid] = (unsigned char)tid;     // identity map at segment base t=0
  }
  __syncthreads();
  float m0 = sbuf[0][0];
  for (int i = 1; i < KK; ++i) m0 = fmaxf(m0, sbuf[0][i]);
  if (ig == 0) sbuf[1][j] = __expf(emb[j] - m0);
  __syncthreads();
  float offset = m0;

  float e_cur = emb[(size_t)KK + j];        // prefetch e for t=1
  for (int t = 1; t < TT; ++t) {
    int p = t & 1, pn = p ^ 1;
    float e = e_cur;
    if (t + 1 < TT) e_cur = emb[(size_t)(t + 1) * KK + j];  // prefetch next
    int m = mrow[t];

    const float4* sv = reinterpret_cast<const float4*>(&sbuf[p][ibase]);
    const float4* dv = reinterpret_cast<const float4*>(&dbuf[p][ibase]);
    float4 s0 = sv[0], s1 = sv[1], s2 = sv[2], s3 = sv[3];
    float4 d0 = dv[0], d1 = dv[1], d2 = dv[2], d3 = dv[3];
    float sown = sbuf[p][j];
    float djj = dbuf[p][j];

    // ---- forward: q_j = (sum_i s_i * E_ij) * exp(e_j) ----
    float q0 = s0.x * E[0] + s0.y * E[1] + s0.z * E[2] + s0.w * E[3];
    float q1 = s1.x * E[4] + s1.y * E[5] + s1.z * E[6] + s1.w * E[7];
    float q2 = s2.x * E[8] + s2.y * E[9] + s2.z * E[10] + s2.w * E[11];
    float q3 = s3.x * E[12] + s3.y * E[13] + s3.z * E[14] + s3.w * E[15];
    float q = (q0 + q1) + (q2 + q3);
    q += __shfl_xor(q, 16);
    q += __shfl_xor(q, 32);
    q *= __expf(e);
    if (!m) q = sown;

    // ---- viterbi: max/argmax_i (delta_i + trans_ij), numpy tie-break ----
    float dd[16];
    dd[0] = d0.x; dd[1] = d0.y; dd[2] = d0.z; dd[3] = d0.w;
    dd[4] = d1.x; dd[5] = d1.y; dd[6] = d1.z; dd[7] = d1.w;
    dd[8] = d2.x; dd[9] = d2.y; dd[10] = d2.z; dd[11] = d2.w;
    dd[12] = d3.x; dd[13] = d3.y; dd[14] = d3.z; dd[15] = d3.w;
    float best = dd[0] + C[0];
    int bidx = ibase;
#pragma unroll
    for (int r = 1; r < 16; ++r) {
      float v = dd[r] + C[r];
      if (v > best) { best = v; bidx = ibase + r; }  // strict >: first max wins
    }
#pragma unroll
    for (int off = 16; off <= 32; off <<= 1) {
      float ob = __shfl_xor(best, off);
      int oi = __shfl_xor(bidx, off);
      bool take = (ob > best) || ((ob == best) && (oi < bidx));
      if (take) { best = ob; bidx = oi; }
    }
    float nd = m ? (best + e) : djj;
    int bpj = m ? bidx : j;
    int mgv = mapb[p][bpj];  // composed: state at t -> state at segment base

    // ---- periodic global renorm of forward vector ----
    if ((t & 3) == 0) {
      float wm = q;
      wm = fmaxf(wm, __shfl_xor(wm, 1));
      wm = fmaxf(wm, __shfl_xor(wm, 2));
      wm = fmaxf(wm, __shfl_xor(wm, 4));
      wm = fmaxf(wm, __shfl_xor(wm, 8));
      wm = fmaxf(wm, __shfl_xor(wm, 16));
      wm = fmaxf(wm, __shfl_xor(wm, 32));
      if (l == 0) wmax[w] = wm;
      __syncthreads();
      float g = fmaxf(fmaxf(wmax[0], wmax[1]), fmaxf(wmax[2], wmax[3]));
      q /= g;
      offset += __logf(g);
    }

    if (ig == 0) {
      sbuf[pn][j] = q;
      dbuf[pn][j] = nd;
      bpl[t][j] = (unsigned char)bpj;
      if ((t & 31) == 0 || t == TT - 1) {
        int s = (t == TT - 1) ? (NSEG - 1) : ((t >> 5) - 1);
        segm[s][j] = (unsigned char)mgv;
        mapb[pn][j] = (unsigned char)j;    // reset to identity at new base
      } else {
        mapb[pn][j] = (unsigned char)mgv;
      }
    }
    __syncthreads();
  }

  // final vectors have parity 0 (t=1023 wrote pn=0)
  if (tid == 0) {
    float ssum = 0.f;
    for (int i = 0; i < KK; ++i) ssum += sbuf[0][i];
    atomicAdd(ll_sum, -(offset + __logf(ssum)));
    float bd = dbuf[0][0];
    int lt = 0;
    for (int i = 1; i < KK; ++i) {
      float v = dbuf[0][i];
      if (v > bd) { bd = v; lt = i; }
    }
    unsigned char x = (unsigned char)lt;
    bound_s[32] = x;                        // state at t=1023
    for (int s = NSEG - 1; s >= 0; --s) {
      x = segm[s][x];
      bound_s[s] = x;                       // state at t=32*s
    }
  }
  __syncthreads();

  // parallel per-segment backtrace from LDS backpointers
  if (tid < NSEG) {
    int s = tid;
    int x = bound_s[s + 1];
    const int* tb = tags + (size_t)b * TT;
    float* ob = out_dec + (size_t)b * TT;
    int cnt = 0;
    int tstart;
    if (s == NSEG - 1) {
      int m = mrow[TT - 1];
      ob[TT - 1] = (float)(m ? x : 0);
      cnt += (m && x == tb[TT - 1]);
      tstart = TT - 1;
    } else {
      tstart = (s + 1) * 32;
    }
    for (int t = tstart; t >= s * 32 + 1; --t) {
      x = bpl[t][x];
      int m2 = mrow[t - 1];
      ob[t - 1] = (float)(m2 ? x : 0);
      cnt += (m2 && x == tb[t - 1]);
    }
    redc[s] = cnt;
  }
  __syncthreads();
  if (tid == 0) {
    int c = 0;
    for (int s = 0; s < NSEG; ++s) c += redc[s];
    atomicAdd(match, c);
  }
}

// ---------------------------------------------------------------------------
// Kernel C: finalize scalars.
// ---------------------------------------------------------------------------
__global__ void finalize_kernel(const float* ll_sum, const int* match,
                                const int* maskSum, float* d_out) {
  d_out[0] = -(*ll_sum) / (float)BB;
  d_out[1 + BB * TT] = (float)(*match) / (float)(*maskSum);
}

extern "C" void kernel_launch(void* const* d_in, const int* in_sizes, int n_in,
                              void* d_out, int out_size, void* d_ws, size_t ws_size,
                              hipStream_t stream) {
  const float* em = (const float*)d_in[0];
  const int* tags = (const int*)d_in[1];
  const int* mask = (const int*)d_in[2];       // bool -> int32 on device
  const float* trans = (const float*)d_in[3];
  float* out = (float*)d_out;

  // scratch: 12 bytes only
  float* ll_sum = (float*)d_ws;
  int* match = (int*)((char*)d_ws + 4);
  int* maskSum = (int*)((char*)d_ws + 8);

  hipMemsetAsync(d_ws, 0, 12, stream);
  score_kernel<<<BB, 256, 0, stream>>>(em, tags, mask, trans, ll_sum, maskSum);
  crf_scan_kernel<<<BB, 256, 0, stream>>>(em, mask, trans, tags, out + 1,
                                          ll_sum, match);
  finalize_kernel<<<1, 1, 0, stream>>>(ll_sum, match, maskSum, out);
}

// Round 4
// 678.323 us; speedup vs baseline: 1.2354x; 1.2354x over previous
//
#include <hip/hip_runtime.h>

#define BB 256
#define TT 1024
#define KK 64

// ---------------------------------------------------------------------------
// Mega-kernel, grid = 512 blocks x 256 threads.
//   blocks [0,256): role 0 = forward logsumexp (waves 0-1) + path score (2-3)
//   blocks [256,512): role 1 = Viterbi (waves 0-1) + backtrace epilogue
// Recurrence layout (waves 0-1): lane l of wave w handles state j=32w+(l&31),
// i-half ig=l>>5 (i in [32ig, 32ig+32)); combine via one shfl_xor(32).
// ---------------------------------------------------------------------------
__global__ __launch_bounds__(256) void crf_mega_kernel(
    const float* __restrict__ em, const int* __restrict__ mask,
    const float* __restrict__ trans, const int* __restrict__ tags,
    float* __restrict__ out_dec, float* ll_sum, int* match, int* maskSum) {

  __shared__ float sd[2][KK];               // s (fwd, exp-domain) or delta (vit)
  __shared__ unsigned char mrow[TT];        // mask row as u8
  __shared__ unsigned char bpl[TT][KK];     // viterbi backpointers (64 KB)
  __shared__ unsigned char segm[32][KK];    // composed 32-step maps
  __shared__ unsigned char bs[40];          // boundary states
  __shared__ int redm[32];

  const int role = (blockIdx.x >= BB) ? 1 : 0;
  const int b = blockIdx.x & (BB - 1);
  const int tid = threadIdx.x;
  const int wv = tid >> 6;
  const int l = tid & 63;

  const float* emb = em + (size_t)b * TT * KK;
  const int* mb = mask + (size_t)b * TT;
  const int* tgb = tags + (size_t)b * TT;

  for (int t = tid; t < TT; t += 256) mrow[t] = (unsigned char)(mb[t] ? 1 : 0);

  const int jl = l & 31;
  const int ig = l >> 5;
  const int j = (wv << 5) + jl;     // valid for wv<2
  const int ibase = ig << 5;

  if (wv < 2 && ig == 0) sd[1][j] = emb[j];   // raw e0: s-init / delta0
  __syncthreads();  // B0

  if (role == 0) {
    // =================== FORWARD (waves 0-1) + SCORE (2-3) ===================
    if (wv < 2) {
      float E[32];
#pragma unroll
      for (int r = 0; r < 32; ++r) E[r] = __expf(trans[(ibase + r) * KK + j]);
      float e_own0 = emb[j];
      float e1 = emb[KK + j];
      float ep[4];
#pragma unroll
      for (int k = 0; k < 4; ++k) ep[k] = emb[(size_t)(2 + k) * KK + j];

      float offset;
      // ---- t = 1 special: exponentiate raw e0 with global max ----
      {
        const float4* rv = reinterpret_cast<const float4*>(&sd[1][ibase]);
        float4 a[8];
#pragma unroll
        for (int k = 0; k < 8; ++k) a[k] = rv[k];
        float raw[32];
#pragma unroll
        for (int k = 0; k < 8; ++k) {
          raw[4*k] = a[k].x; raw[4*k+1] = a[k].y;
          raw[4*k+2] = a[k].z; raw[4*k+3] = a[k].w;
        }
        float g0 = fmaxf(raw[0], raw[1]);
#pragma unroll
        for (int r = 2; r < 32; r += 2) g0 = fmaxf(g0, fmaxf(raw[r], raw[r+1]));
        float m0 = fmaxf(g0, __shfl_xor(g0, 32));
        offset = m0;
        float q = 0.f;
#pragma unroll
        for (int r = 0; r < 32; ++r) q += __expf(raw[r] - m0) * E[r];
        q += __shfl_xor(q, 32);
        q *= __expf(e1);
        float sown = __expf(e_own0 - m0);
        q = mrow[1] ? q : sown;
        if (ig == 0) sd[0][j] = q;
      }
      __syncthreads();  // t=1

      auto fwd_body = [&](int t, float e) {
        int p = t & 1, pn = p ^ 1;
        const float4* sv = reinterpret_cast<const float4*>(&sd[p][ibase]);
        float4 a[8];
#pragma unroll
        for (int k = 0; k < 8; ++k) a[k] = sv[k];
        float sown = sd[p][j];
        float q0 = 0.f, q1 = 0.f, q2 = 0.f, q3 = 0.f;
#pragma unroll
        for (int k = 0; k < 8; k += 4) {
          q0 += a[k].x * E[4*k]     + a[k].y * E[4*k+1]
              + a[k].z * E[4*k+2]   + a[k].w * E[4*k+3];
          q1 += a[k+1].x * E[4*k+4] + a[k+1].y * E[4*k+5]
              + a[k+1].z * E[4*k+6] + a[k+1].w * E[4*k+7];
          q2 += a[k+2].x * E[4*k+8] + a[k+2].y * E[4*k+9]
              + a[k+2].z * E[4*k+10]+ a[k+2].w * E[4*k+11];
          q3 += a[k+3].x * E[4*k+12]+ a[k+3].y * E[4*k+13]
              + a[k+3].z * E[4*k+14]+ a[k+3].w * E[4*k+15];
        }
        float q = (q0 + q1) + (q2 + q3);
        q += __shfl_xor(q, 32);
        q *= __expf(e);
        q = mrow[t] ? q : sown;
        if ((t & 7) == 0) {   // barrier-free renorm: max of pre-update s
          float gm = fmaxf(fmaxf(a[0].x, a[0].y), fmaxf(a[0].z, a[0].w));
#pragma unroll
          for (int k = 1; k < 8; ++k)
            gm = fmaxf(gm, fmaxf(fmaxf(a[k].x, a[k].y), fmaxf(a[k].z, a[k].w)));
          gm = fmaxf(gm, __shfl_xor(gm, 32));
          q *= __builtin_amdgcn_rcpf(gm);
          offset += __logf(gm);
        }
        if (ig == 0) sd[pn][j] = q;
        __syncthreads();
      };

      int tb = 2;
      for (; tb + 3 <= TT - 1; tb += 4) {
#pragma unroll
        for (int k = 0; k < 4; ++k) {
          int t = tb + k;
          float e = ep[k];
          int tpre = t + 4; if (tpre > TT - 1) tpre = TT - 1;
          ep[k] = emb[(size_t)tpre * KK + j];
          fwd_body(t, e);
        }
      }
      for (int t = tb; t <= TT - 1; ++t) fwd_body(t, ep[(t - 2) & 3]);

      if (tid == 0) {   // final parity 0
        float ssum = 0.f;
        for (int i = 0; i < KK; ++i) ssum += sd[0][i];
        atomicAdd(ll_sum, -(offset + __logf(ssum)));
      }
    } else {
      // ---- score waves: gather path score, then barrier-match the loop ----
      int t2 = tid - 128;  // 0..127
      float acc = 0.f;
      int cnt = 0;
      for (int t = t2; t < TT; t += 128) {
        if (mb[t]) {
          int tg = tgb[t];
          acc += emb[(size_t)t * KK + tg];
          cnt += 1;
          if (t >= 1) acc += trans[tgb[t - 1] * KK + tg];
        }
      }
#pragma unroll
      for (int off = 1; off <= 32; off <<= 1) {
        acc += __shfl_xor(acc, off);
        cnt += __shfl_xor(cnt, off);
      }
      if (l == 0) { atomicAdd(ll_sum, acc); atomicAdd(maskSum, cnt); }
      for (int it = 0; it < TT - 1; ++it) __syncthreads();  // match 1023
    }
  } else {
    // ============================ VITERBI ============================
    if (wv < 2) {
      float C[32];
#pragma unroll
      for (int r = 0; r < 32; ++r) C[r] = trans[(ibase + r) * KK + j];
      float ep[4];
#pragma unroll
      for (int k = 0; k < 4; ++k) ep[k] = emb[(size_t)(1 + k) * KK + j];

      auto vit_body = [&](int t, float e) {
        int p = t & 1, pn = p ^ 1;
        const float4* dv = reinterpret_cast<const float4*>(&sd[p][ibase]);
        float4 a[8];
#pragma unroll
        for (int k = 0; k < 8; ++k) a[k] = dv[k];
        float down = sd[p][j];
        float v[32];
#pragma unroll
        for (int k = 0; k < 8; ++k) {
          v[4*k]   = a[k].x + C[4*k];
          v[4*k+1] = a[k].y + C[4*k+1];
          v[4*k+2] = a[k].z + C[4*k+2];
          v[4*k+3] = a[k].w + C[4*k+3];
        }
        // tournament tree, ties -> lower index (matches numpy argmax)
        float tv[16]; int ti[16];
#pragma unroll
        for (int k = 0; k < 16; ++k) {
          bool tk = v[2*k+1] > v[2*k];
          tv[k] = tk ? v[2*k+1] : v[2*k];
          ti[k] = tk ? 2*k+1 : 2*k;
        }
#pragma unroll
        for (int st = 8; st >= 1; st >>= 1) {
#pragma unroll
          for (int k = 0; k < 16; ++k) {   // only k<st live; rest folded out
            if (k < st) {
              bool tk = tv[k+st] > tv[k];
              tv[k] = tk ? tv[k+st] : tv[k];
              ti[k] = tk ? ti[k+st] : ti[k];
            }
          }
        }
        float best = tv[0];
        int bidx = ibase + ti[0];
        float ob = __shfl_xor(best, 32);
        int oi = __shfl_xor(bidx, 32);
        bool take = (ob > best) || ((ob == best) && (oi < bidx));
        best = take ? ob : best;
        bidx = take ? oi : bidx;
        int m = mrow[t];
        float nd = m ? (best + e) : down;
        int bp = m ? bidx : j;
        if (ig == 0) {
          sd[pn][j] = nd;
          bpl[t][j] = (unsigned char)bp;
        }
        __syncthreads();
      };

      int tb = 1;
      for (; tb + 3 <= TT - 1; tb += 4) {
#pragma unroll
        for (int k = 0; k < 4; ++k) {
          int t = tb + k;
          float e = ep[k];
          int tpre = t + 4; if (tpre > TT - 1) tpre = TT - 1;
          ep[k] = emb[(size_t)tpre * KK + j];
          vit_body(t, e);
        }
      }
      for (int t = tb; t <= TT - 1; ++t) vit_body(t, ep[(t - 1) & 3]);
    } else {
      for (int it = 0; it < TT - 1; ++it) __syncthreads();  // match 1023
    }

    // ---- epilogue: compose segment maps (8 chains/thread, ILP) ----
    {
      int j0 = tid & 63;
      int s0 = tid >> 6;     // chain kk: s = s0 + 4*kk
      int xs[8];
#pragma unroll
      for (int kk = 0; kk < 8; ++kk) xs[kk] = j0;
      int tEnd[8], tStart[8];
#pragma unroll
      for (int kk = 0; kk < 8; ++kk) {
        int s = s0 + 4 * kk;
        tStart[kk] = 32 * s + 1;
        tEnd[kk] = (s == 31) ? (TT - 1) : (32 * s + 32);
      }
      for (int q = 0; q < 32; ++q) {
#pragma unroll
        for (int kk = 0; kk < 8; ++kk) {
          int t = tEnd[kk] - q;
          if (t >= tStart[kk]) xs[kk] = bpl[t][xs[kk]];
        }
      }
#pragma unroll
      for (int kk = 0; kk < 8; ++kk) segm[s0 + 4 * kk][j0] = (unsigned char)xs[kk];
    }
    __syncthreads();

    if (tid == 0) {   // last_tag argmax (parity 0) + boundary walk
      float bd = sd[0][0];
      int lt = 0;
      for (int i = 1; i < KK; ++i) {
        float v2 = sd[0][i];
        if (v2 > bd) { bd = v2; lt = i; }
      }
      bs[32] = (unsigned char)lt;
      for (int s = 31; s >= 0; --s) bs[s] = segm[s][bs[s + 1]];
    }
    __syncthreads();

    if (tid < 32) {   // per-segment backtrace
      int s = tid;
      int x = bs[s + 1];
      int cnt = 0;
      int tEnd = (s == 31) ? (TT - 1) : (32 * s + 32);
      if (s == 31) {
        int m = mrow[TT - 1];
        out_dec[(size_t)b * TT + TT - 1] = (float)(m ? x : 0);
        cnt += (m && x == tgb[TT - 1]);
      }
      for (int t = tEnd; t >= 32 * s + 1; --t) {
        x = bpl[t][x];
        int m2 = mrow[t - 1];
        out_dec[(size_t)b * TT + t - 1] = (float)(m2 ? x : 0);
        cnt += (m2 && x == tgb[t - 1]);
      }
      redm[s] = cnt;
    }
    __syncthreads();
    if (tid == 0) {
      int c = 0;
      for (int s = 0; s < 32; ++s) c += redm[s];
      atomicAdd(match, c);
    }
  }
}

__global__ void finalize_kernel(const float* ll_sum, const int* match,
                                const int* maskSum, float* d_out) {
  d_out[0] = -(*ll_sum) / (float)BB;
  d_out[1 + BB * TT] = (float)(*match) / (float)(*maskSum);
}

extern "C" void kernel_launch(void* const* d_in, const int* in_sizes, int n_in,
                              void* d_out, int out_size, void* d_ws, size_t ws_size,
                              hipStream_t stream) {
  const float* em = (const float*)d_in[0];
  const int* tags = (const int*)d_in[1];
  const int* mask = (const int*)d_in[2];       // bool -> int32 on device
  const float* trans = (const float*)d_in[3];
  float* out = (float*)d_out;

  float* ll_sum = (float*)d_ws;
  int* match = (int*)((char*)d_ws + 4);
  int* maskSum = (int*)((char*)d_ws + 8);

  hipMemsetAsync(d_ws, 0, 12, stream);
  crf_mega_kernel<<<2 * BB, 256, 0, stream>>>(em, mask, trans, tags, out + 1,
                                              ll_sum, match, maskSum);
  finalize_kernel<<<1, 1, 0, stream>>>(ll_sum, match, maskSum, out);
}